// Round 3
// baseline (4971.663 us; speedup 1.0000x reference)
//
#include <hip/hip_runtime.h>
#include <math.h>

// Model: PINNDamageLocator
// conv1: (288,4,32,2048) -> bn+relu -> pool -> (288,16,16,512), SE1
// conv2: -> bn+relu -> pool -> (288,32,8,128), SE2
// conv3: -> bn+relu -> mean -> (288,64)
// then edge_fc + GNN + attention heads -> (reg[8,3], cls[8,9], ea[8,36])
//
// Each thread owns ONE pooled output column; the 4 input rows feeding the
// 2x2 pooling window are loaded ONCE per ci (aligned float4 + 1 halo scalar),
// accumulating acc[2 conv rows][2 conv cols][co] in registers. BN scale (+ SE
// scale for conv2/3) folded into LDS weights; BN shift + bias folded per-co.
// __launch_bounds__(256,4) pins VGPR<=128 for 4 waves/SIMD.

// ---------------- conv1 + bn1 + relu + maxpool + SE1-sum ----------------
__global__ __launch_bounds__(256, 4) void k_conv1(
    const float* __restrict__ x, const float* __restrict__ w,
    const float* __restrict__ cb, const float* __restrict__ bs,
    const float* __restrict__ bb, const float* __restrict__ bm,
    const float* __restrict__ bv,
    float* __restrict__ h1, float* __restrict__ sesum)
{
  int bid = blockIdx.x;                  // n*32 + ph*2 + half
  int n = bid >> 5, rem = bid & 31, ph = rem >> 1, half = rem & 1;
  int pw = (half << 8) + threadIdx.x;    // pooled col 0..511
  __shared__ float wl[4][3][3][16];      // [ci][kh][kw][co], bn-scale folded
  __shared__ float bi[16];
  for (int i = threadIdx.x; i < 576; i += 256) {
    int co = i / 36, r = i % 36, ci = r / 9, kk = r % 9;
    float s = bs[co] * rsqrtf(bv[co] + 1e-5f);
    wl[ci][kk / 3][kk % 3][co] = w[i] * s;
  }
  if (threadIdx.x < 16) {
    int c = threadIdx.x;
    float s = bs[c] * rsqrtf(bv[c] + 1e-5f);
    bi[c] = bb[c] + (cb[c] - bm[c]) * s;
  }
  __syncthreads();
  const float* xn = x + (size_t)n * 4 * 32 * 2048;
  const bool r0ok = (ph > 0), r3ok = (ph < 15);
  const int col4 = 4 * pw;
  float acc[2][2][16];
#pragma unroll
  for (int cr = 0; cr < 2; cr++)
#pragma unroll
    for (int cc = 0; cc < 2; cc++)
#pragma unroll
      for (int co = 0; co < 16; co++) acc[cr][cc][co] = 0.f;
#pragma unroll
  for (int ci = 0; ci < 4; ci++) {
    const float* base = xn + (ci * 32 + 2 * ph - 1) * 2048;
    float strip[4][5];
#pragma unroll
    for (int r = 0; r < 4; r++) {
      bool ok = (r == 0) ? r0ok : ((r == 3) ? r3ok : true);
      const float* xr = base + r * 2048;
      if (ok) {
        float4 v4 = *reinterpret_cast<const float4*>(xr + col4);
        strip[r][0] = pw ? xr[col4 - 1] : 0.f;
        strip[r][1] = v4.x; strip[r][2] = v4.y; strip[r][3] = v4.z; strip[r][4] = v4.w;
      } else {
        strip[r][0] = strip[r][1] = strip[r][2] = strip[r][3] = strip[r][4] = 0.f;
      }
    }
#pragma unroll
    for (int cr = 0; cr < 2; cr++) {
#pragma unroll
      for (int kh = 0; kh < 3; kh++) {
        int r = cr + kh;
#pragma unroll
        for (int kw = 0; kw < 3; kw++) {
          float v0 = strip[r][kw], v1 = strip[r][2 + kw];
#pragma unroll
          for (int co = 0; co < 16; co++) {
            float wv = wl[ci][kh][kw][co];
            acc[cr][0][co] = fmaf(v0, wv, acc[cr][0][co]);
            acc[cr][1][co] = fmaf(v1, wv, acc[cr][1][co]);
          }
        }
      }
    }
  }
  float pooled[16];
#pragma unroll
  for (int co = 0; co < 16; co++) {
    float m = fmaxf(fmaxf(acc[0][0][co], acc[0][1][co]),
                    fmaxf(acc[1][0][co], acc[1][1][co]));
    pooled[co] = fmaxf(m + bi[co], 0.f);
    h1[(((size_t)n * 16 + co) * 16 + ph) * 512 + pw] = pooled[co];
  }
  int lane = threadIdx.x & 63;
#pragma unroll
  for (int co = 0; co < 16; co++) {
    float v = pooled[co];
    for (int off = 32; off; off >>= 1) v += __shfl_down(v, off);
    if (lane == 0) atomicAdd(&sesum[n * 16 + co], v);
  }
}

// ---------------- SE MLP (generic): mean -> relu fc -> sigmoid fc ----------------
__global__ void k_se(const float* __restrict__ sesum, int C, int Cr, float invcnt,
                     const float* __restrict__ w1, const float* __restrict__ b1,
                     const float* __restrict__ w2, const float* __restrict__ b2,
                     float* __restrict__ s)
{
  int n = blockIdx.x * blockDim.x + threadIdx.x;
  if (n >= 288) return;
  float y[32], t[8];
  for (int c = 0; c < C; c++) y[c] = sesum[n * C + c] * invcnt;
  for (int r = 0; r < Cr; r++) {
    float a = b1[r];
    for (int c = 0; c < C; c++) a += y[c] * w1[r * C + c];
    t[r] = fmaxf(a, 0.f);
  }
  for (int c = 0; c < C; c++) {
    float a = b2[c];
    for (int r = 0; r < Cr; r++) a += t[r] * w2[c * Cr + r];
    s[n * C + c] = 1.f / (1.f + expf(-a));
  }
}

// ---------------- conv2 (SE1 folded) + bn2 + relu + pool + SE2-sum ----------------
__global__ __launch_bounds__(256, 4) void k_conv2(
    const float* __restrict__ h1, const float* __restrict__ w,
    const float* __restrict__ cb, const float* __restrict__ bs,
    const float* __restrict__ bb, const float* __restrict__ bm,
    const float* __restrict__ bv,
    const float* __restrict__ s1,
    float* __restrict__ h2, float* __restrict__ sesum)
{
  int bid = blockIdx.x;                 // n*8 + ph
  int n = bid >> 3, ph = bid & 7;
  int cog = threadIdx.x >> 7;           // co half: cog*16..cog*16+15
  int wp = threadIdx.x & 127;           // pooled col 0..127
  __shared__ float wl[16][3][3][32];    // bn scale * se1 scale folded
  __shared__ float bi[32];
  const float* s1n = s1 + n * 16;
  for (int i = threadIdx.x; i < 4608; i += 256) {
    int co = i / 144, r = i % 144, ci = r / 9, kk = r % 9;
    float s = bs[co] * rsqrtf(bv[co] + 1e-5f);
    wl[ci][kk / 3][kk % 3][co] = w[i] * s * s1n[ci];
  }
  if (threadIdx.x < 32) {
    int c = threadIdx.x;
    float s = bs[c] * rsqrtf(bv[c] + 1e-5f);
    bi[c] = bb[c] + (cb[c] - bm[c]) * s;
  }
  __syncthreads();
  const float* hn = h1 + (size_t)n * 16 * 16 * 512;
  const bool r0ok = (ph > 0), r3ok = (ph < 7);
  const int col4 = 4 * wp;
  const int cob = cog * 16;
  float acc[2][2][16];
#pragma unroll
  for (int cr = 0; cr < 2; cr++)
#pragma unroll
    for (int cc = 0; cc < 2; cc++)
#pragma unroll
      for (int co = 0; co < 16; co++) acc[cr][cc][co] = 0.f;
#pragma unroll 2
  for (int ci = 0; ci < 16; ci++) {
    const float* base = hn + (ci * 16 + 2 * ph - 1) * 512;
    float strip[4][5];
#pragma unroll
    for (int r = 0; r < 4; r++) {
      bool ok = (r == 0) ? r0ok : ((r == 3) ? r3ok : true);
      const float* hr = base + r * 512;
      if (ok) {
        float4 v4 = *reinterpret_cast<const float4*>(hr + col4);
        strip[r][0] = wp ? hr[col4 - 1] : 0.f;
        strip[r][1] = v4.x; strip[r][2] = v4.y; strip[r][3] = v4.z; strip[r][4] = v4.w;
      } else {
        strip[r][0] = strip[r][1] = strip[r][2] = strip[r][3] = strip[r][4] = 0.f;
      }
    }
#pragma unroll
    for (int cr = 0; cr < 2; cr++) {
#pragma unroll
      for (int kh = 0; kh < 3; kh++) {
        int r = cr + kh;
#pragma unroll
        for (int kw = 0; kw < 3; kw++) {
          float v0 = strip[r][kw], v1 = strip[r][2 + kw];
#pragma unroll
          for (int co = 0; co < 16; co++) {
            float wv = wl[ci][kh][kw][cob + co];
            acc[cr][0][co] = fmaf(v0, wv, acc[cr][0][co]);
            acc[cr][1][co] = fmaf(v1, wv, acc[cr][1][co]);
          }
        }
      }
    }
  }
  float pooled[16];
#pragma unroll
  for (int co = 0; co < 16; co++) {
    float m = fmaxf(fmaxf(acc[0][0][co], acc[0][1][co]),
                    fmaxf(acc[1][0][co], acc[1][1][co]));
    pooled[co] = fmaxf(m + bi[cob + co], 0.f);
    h2[(((size_t)n * 32 + cob + co) * 8 + ph) * 128 + wp] = pooled[co];
  }
  int lane = threadIdx.x & 63;
#pragma unroll
  for (int co = 0; co < 16; co++) {
    float v = pooled[co];
    for (int off = 32; off; off >>= 1) v += __shfl_down(v, off);
    if (lane == 0) atomicAdd(&sesum[n * 32 + cob + co], v);
  }
}

// ---------------- conv3 (SE2 folded) + bn3 + relu + global mean ----------------
__global__ __launch_bounds__(256, 4) void k_conv3(
    const float* __restrict__ h2, const float* __restrict__ w,
    const float* __restrict__ cb, const float* __restrict__ bs,
    const float* __restrict__ bb, const float* __restrict__ bm,
    const float* __restrict__ bv,
    const float* __restrict__ s2, float* __restrict__ h3)
{
  int bid = blockIdx.x;                 // n*2 + cog (32 out channels per cog)
  int n = bid >> 1, cog = bid & 1;
  int hh = threadIdx.x >> 5;            // conv row 0..7
  int t = threadIdx.x & 31;             // conv col pair: cols 2t, 2t+1
  __shared__ float wl[32][3][3][32];    // [ci][kh][kw][k], 36 KB, scales folded
  __shared__ float bi[32];
  __shared__ float red[4][32];
  const float* s2n = s2 + n * 32;
  for (int i = threadIdx.x; i < 9216; i += 256) {
    int k = i / 288, r = i % 288, ci = r / 9, kk = r % 9;
    int co = cog * 32 + k;
    float s = bs[co] * rsqrtf(bv[co] + 1e-5f);
    wl[ci][kk / 3][kk % 3][k] = w[(size_t)co * 288 + r] * s * s2n[ci];
  }
  if (threadIdx.x < 32) {
    int c = cog * 32 + threadIdx.x;
    float s = bs[c] * rsqrtf(bv[c] + 1e-5f);
    bi[threadIdx.x] = bb[c] + (cb[c] - bm[c]) * s;
  }
  __syncthreads();
  const float* hn = h2 + (size_t)n * 32 * 8 * 128;
  const bool r0ok = (hh > 0), r2ok = (hh < 7);
  const int col4 = 4 * t;
  float acc[2][32];
#pragma unroll
  for (int cc = 0; cc < 2; cc++)
#pragma unroll
    for (int k = 0; k < 32; k++) acc[cc][k] = 0.f;
#pragma unroll 2
  for (int ci = 0; ci < 32; ci++) {
    const float* base = hn + (ci * 8 + hh - 1) * 128;
    float strip[3][5];
#pragma unroll
    for (int r = 0; r < 3; r++) {
      bool ok = (r == 0) ? r0ok : ((r == 2) ? r2ok : true);
      const float* hr = base + r * 128;
      if (ok) {
        float4 v4 = *reinterpret_cast<const float4*>(hr + col4);
        strip[r][0] = t ? hr[col4 - 1] : 0.f;
        strip[r][1] = v4.x; strip[r][2] = v4.y; strip[r][3] = v4.z; strip[r][4] = v4.w;
      } else {
        strip[r][0] = strip[r][1] = strip[r][2] = strip[r][3] = strip[r][4] = 0.f;
      }
    }
#pragma unroll
    for (int kh = 0; kh < 3; kh++) {
#pragma unroll
      for (int kw = 0; kw < 3; kw++) {
        float v0 = strip[kh][kw], v1 = strip[kh][2 + kw];
#pragma unroll
        for (int k = 0; k < 32; k++) {
          float wv = wl[ci][kh][kw][k];
          acc[0][k] = fmaf(v0, wv, acc[0][k]);
          acc[1][k] = fmaf(v1, wv, acc[1][k]);
        }
      }
    }
  }
#pragma unroll
  for (int k = 0; k < 32; k++)
    acc[0][k] = fmaxf(acc[0][k] + bi[k], 0.f) + fmaxf(acc[1][k] + bi[k], 0.f);
  int lane = threadIdx.x & 63, wv = threadIdx.x >> 6;
#pragma unroll
  for (int k = 0; k < 32; k++) {
    float v = acc[0][k];
    for (int off = 32; off; off >>= 1) v += __shfl_down(v, off);
    if (lane == 0) red[wv][k] = v;
  }
  __syncthreads();
  if (threadIdx.x < 32) {
    int k = threadIdx.x;
    float tt = red[0][k] + red[1][k] + red[2][k] + red[3][k];
    h3[n * 64 + cog * 32 + k] = tt * (1.f / 512.f);
  }
}

// ---------------- head: edge_fc + GNN scatter + e2n + attention + outputs ----------------
__global__ __launch_bounds__(256) void k_head(
    const float* __restrict__ h3,
    const float* __restrict__ efw, const float* __restrict__ efb,
    const float* __restrict__ ew,
    const float* __restrict__ e2nw, const float* __restrict__ e2nb,
    const float* __restrict__ a1w, const float* __restrict__ a1b,
    const float* __restrict__ a2w,
    const float* __restrict__ clsw, const float* __restrict__ clsb,
    const float* __restrict__ regw, const float* __restrict__ regb,
    float* __restrict__ out)
{
  int b = blockIdx.x;
  int tid = threadIdx.x;
  __shared__ float ef[36][64];      // weighted edge features
  __shared__ float nin[12][64];
  __shared__ float nd[12][128];
  __shared__ float tmp[12][64];
  __shared__ float spw[36], aw[12], scv[12], g[128], ea[36];
  if (tid < 36) {
    float xw = ew[tid];
    spw[tid] = (xw > 20.f) ? xw : log1pf(expf(xw));   // softplus
  }
  __syncthreads();
  for (int idx = tid; idx < 36 * 64; idx += 256) {
    int e = idx >> 6, d = idx & 63;
    const float* hr = h3 + (size_t)(b * 36 + e) * 64;
    const float* wr = efw + d * 64;
    float a = efb[d];
    for (int k = 0; k < 64; k++) a += hr[k] * wr[k];
    ef[e][d] = fmaxf(a, 0.f) * spw[e];
  }
  __syncthreads();
  for (int idx = tid; idx < 12 * 64; idx += 256) {
    int j = idx >> 6, d = idx & 63;
    float a = 0.f;
    if (j < 6) { for (int i = 0; i < 6; i++) a += ef[j * 6 + i][d]; }
    else       { for (int i = 0; i < 6; i++) a += ef[i * 6 + (j - 6)][d]; }
    nin[j][d] = a;
  }
  __syncthreads();
  for (int idx = tid; idx < 12 * 128; idx += 256) {
    int j = idx >> 7, d = idx & 127;
    const float* wr = e2nw + d * 64;
    float a = e2nb[d];
    for (int k = 0; k < 64; k++) a += nin[j][k] * wr[k];
    nd[j][d] = fmaxf(a, 0.f);
  }
  __syncthreads();
  for (int idx = tid; idx < 12 * 64; idx += 256) {
    int j = idx >> 6, hh = idx & 63;
    const float* wr = a1w + hh * 128;
    float a = a1b[hh];
    for (int k = 0; k < 128; k++) a += nd[j][k] * wr[k];
    tmp[j][hh] = tanhf(a) * a2w[hh];
  }
  __syncthreads();
  if (tid < 12) {
    float a = 0.f;
    for (int h = 0; h < 64; h++) a += tmp[tid][h];
    scv[tid] = a;
  }
  __syncthreads();
  if (tid == 0) {
    float m = scv[0];
    for (int j = 1; j < 12; j++) m = fmaxf(m, scv[j]);
    float s = 0.f;
    for (int j = 0; j < 12; j++) { float z = expf(scv[j] - m); aw[j] = z; s += z; }
    float inv = 1.f / s;
    for (int j = 0; j < 12; j++) aw[j] *= inv;
    float rs = 0.f;
    for (int e = 0; e < 36; e++) { float r = aw[e / 6] * aw[6 + e % 6]; ea[e] = r; rs += r; }
    float inv2 = 1.f / (rs + 1e-8f);
    for (int e = 0; e < 36; e++) ea[e] *= inv2;
  }
  __syncthreads();
  if (tid < 36) out[96 + b * 36 + tid] = ea[tid];
  if (tid < 128) {
    float a = 0.f;
    for (int j = 0; j < 12; j++) a += nd[j][tid] * aw[j];
    g[tid] = a;
  }
  __syncthreads();
  if (tid < 3) {
    const float* wr = regw + tid * 128;
    float a = regb[tid];
    for (int k = 0; k < 128; k++) a += g[k] * wr[k];
    out[b * 3 + tid] = a;
  }
  if (tid >= 64 && tid < 73) {
    int i = tid - 64;
    const float* wr = clsw + i * 128;
    float a = clsb[i];
    for (int k = 0; k < 128; k++) a += g[k] * wr[k];
    out[24 + b * 9 + i] = a;
  }
}

extern "C" void kernel_launch(void* const* d_in, const int* in_sizes, int n_in,
                              void* d_out, int out_size, void* d_ws, size_t ws_size,
                              hipStream_t stream) {
  const float* x      = (const float*)d_in[0];
  const float* c1w    = (const float*)d_in[1];
  const float* c1b    = (const float*)d_in[2];
  const float* bn1s   = (const float*)d_in[3];
  const float* bn1b   = (const float*)d_in[4];
  const float* bn1m   = (const float*)d_in[5];
  const float* bn1v   = (const float*)d_in[6];
  const float* se1w1  = (const float*)d_in[7];
  const float* se1b1  = (const float*)d_in[8];
  const float* se1w2  = (const float*)d_in[9];
  const float* se1b2  = (const float*)d_in[10];
  const float* c2w    = (const float*)d_in[11];
  const float* c2b    = (const float*)d_in[12];
  const float* bn2s   = (const float*)d_in[13];
  const float* bn2b   = (const float*)d_in[14];
  const float* bn2m   = (const float*)d_in[15];
  const float* bn2v   = (const float*)d_in[16];
  const float* se2w1  = (const float*)d_in[17];
  const float* se2b1  = (const float*)d_in[18];
  const float* se2w2  = (const float*)d_in[19];
  const float* se2b2  = (const float*)d_in[20];
  const float* c3w    = (const float*)d_in[21];
  const float* c3b    = (const float*)d_in[22];
  const float* bn3s   = (const float*)d_in[23];
  const float* bn3b   = (const float*)d_in[24];
  const float* bn3m   = (const float*)d_in[25];
  const float* bn3v   = (const float*)d_in[26];
  const float* efw    = (const float*)d_in[27];
  const float* efb    = (const float*)d_in[28];
  const float* ew     = (const float*)d_in[29];
  const float* e2nw   = (const float*)d_in[30];
  const float* e2nb   = (const float*)d_in[31];
  const float* a1w    = (const float*)d_in[32];
  const float* a1b    = (const float*)d_in[33];
  const float* a2w    = (const float*)d_in[34];
  const float* clsw   = (const float*)d_in[35];
  const float* clsb   = (const float*)d_in[36];
  const float* regw   = (const float*)d_in[37];
  const float* regb   = (const float*)d_in[38];

  float* ws = (float*)d_ws;
  float* h1     = ws;                        // 288*16*16*512 = 37,748,736 f
  float* h2     = h1 + 37748736;             // 288*32*8*128  =  9,437,184 f
  float* sesum1 = h2 + 9437184;              // 4608 f
  float* s1     = sesum1 + 4608;             // 4608 f
  float* sesum2 = s1 + 4608;                 // 9216 f
  float* s2     = sesum2 + 9216;             // 9216 f
  float* h3     = s2 + 9216;                 // 18432 f

  hipMemsetAsync(sesum1, 0, 4608 * sizeof(float), stream);
  hipMemsetAsync(sesum2, 0, 9216 * sizeof(float), stream);

  k_conv1<<<288 * 32, 256, 0, stream>>>(x, c1w, c1b, bn1s, bn1b, bn1m, bn1v, h1, sesum1);
  k_se<<<5, 64, 0, stream>>>(sesum1, 16, 4, 1.f / 8192.f, se1w1, se1b1, se1w2, se1b2, s1);
  k_conv2<<<288 * 8, 256, 0, stream>>>(h1, c2w, c2b, bn2s, bn2b, bn2m, bn2v, s1, h2, sesum2);
  k_se<<<5, 64, 0, stream>>>(sesum2, 32, 8, 1.f / 1024.f, se2w1, se2b1, se2w2, se2b2, s2);
  k_conv3<<<288 * 2, 256, 0, stream>>>(h2, c3w, c3b, bn3s, bn3b, bn3m, bn3v, s2, h3);
  k_head<<<8, 256, 0, stream>>>(h3, efw, efb, ew, e2nw, e2nb, a1w, a1b, a2w,
                                clsw, clsb, regw, regb, (float*)d_out);
}

// Round 4
// 1433.282 us; speedup vs baseline: 3.4687x; 3.4687x over previous
//
#include <hip/hip_runtime.h>
#include <math.h>

// Model: PINNDamageLocator
// conv1: (288,4,32,2048) -> bn+relu -> pool -> (288,16,16,512), SE1
// conv2: -> bn+relu -> pool -> (288,32,8,128), SE2
// conv3: -> bn+relu -> mean -> (288,64)
// then edge_fc + GNN + attention heads -> (reg[8,3], cls[8,9], ea[8,36])
//
// Dataflow: each thread owns ONE pooled output column and a SLICE (8 or 16)
// of output channels (co split across thread groups -> acc[2][2][8] = 32
// VGPRs, no spill, 4+ waves/SIMD). The 4 input rows feeding the 2x2 pooling
// window are loaded ONCE per ci as a batch of independent float4+halo loads.
// BN scale (+ SE scale) folded into LDS weights; BN shift + bias per-co.
// NOTE: do NOT use __launch_bounds__ min-waves arg — (256,4) forced VGPR=64
// and spilled acc to scratch (4.5 GB of HBM writes, R3 post-mortem).

// ---------------- conv1 + bn1 + relu + maxpool + SE1-sum ----------------
__global__ __launch_bounds__(512) void k_conv1(
    const float* __restrict__ x, const float* __restrict__ w,
    const float* __restrict__ cb, const float* __restrict__ bs,
    const float* __restrict__ bb, const float* __restrict__ bm,
    const float* __restrict__ bv,
    float* __restrict__ h1, float* __restrict__ sesum)
{
  int bid = blockIdx.x;                  // n*32 + ph*2 + half
  int n = bid >> 5, rem = bid & 31, ph = rem >> 1, half = rem & 1;
  int cog = threadIdx.x >> 8;            // 0,1 -> co slice cog*8..cog*8+7
  int pw = (half << 8) + (threadIdx.x & 255);   // pooled col 0..511
  __shared__ float wl[4][3][3][16];      // [ci][kh][kw][co], bn-scale folded
  __shared__ float bi[16];
  for (int i = threadIdx.x; i < 576; i += 512) {
    int co = i / 36, r = i % 36, ci = r / 9, kk = r % 9;
    float s = bs[co] * rsqrtf(bv[co] + 1e-5f);
    wl[ci][kk / 3][kk % 3][co] = w[i] * s;
  }
  if (threadIdx.x < 16) {
    int c = threadIdx.x;
    float s = bs[c] * rsqrtf(bv[c] + 1e-5f);
    bi[c] = bb[c] + (cb[c] - bm[c]) * s;
  }
  __syncthreads();
  const float* xn = x + (size_t)n * 4 * 32 * 2048;
  const bool r0ok = (ph > 0), r3ok = (ph < 15);
  const int col4 = 4 * pw;
  const int cob = cog * 8;
  float acc[2][2][8];
#pragma unroll
  for (int cr = 0; cr < 2; cr++)
#pragma unroll
    for (int cc = 0; cc < 2; cc++)
#pragma unroll
      for (int co = 0; co < 8; co++) acc[cr][cc][co] = 0.f;
#pragma unroll
  for (int ci = 0; ci < 4; ci++) {
    const float* base = xn + (ci * 32 + 2 * ph - 1) * 2048;
    float strip[4][5];
#pragma unroll
    for (int r = 0; r < 4; r++) {
      bool ok = (r == 0) ? r0ok : ((r == 3) ? r3ok : true);
      const float* xr = base + r * 2048;
      if (ok) {
        float4 v4 = *reinterpret_cast<const float4*>(xr + col4);
        strip[r][0] = pw ? xr[col4 - 1] : 0.f;
        strip[r][1] = v4.x; strip[r][2] = v4.y; strip[r][3] = v4.z; strip[r][4] = v4.w;
      } else {
        strip[r][0] = strip[r][1] = strip[r][2] = strip[r][3] = strip[r][4] = 0.f;
      }
    }
#pragma unroll
    for (int cr = 0; cr < 2; cr++) {
#pragma unroll
      for (int kh = 0; kh < 3; kh++) {
        int r = cr + kh;
#pragma unroll
        for (int kw = 0; kw < 3; kw++) {
          float v0 = strip[r][kw], v1 = strip[r][2 + kw];
#pragma unroll
          for (int co = 0; co < 8; co++) {
            float wv = wl[ci][kh][kw][cob + co];
            acc[cr][0][co] = fmaf(v0, wv, acc[cr][0][co]);
            acc[cr][1][co] = fmaf(v1, wv, acc[cr][1][co]);
          }
        }
      }
    }
  }
  float pooled[8];
#pragma unroll
  for (int co = 0; co < 8; co++) {
    float m = fmaxf(fmaxf(acc[0][0][co], acc[0][1][co]),
                    fmaxf(acc[1][0][co], acc[1][1][co]));
    pooled[co] = fmaxf(m + bi[cob + co], 0.f);
    h1[(((size_t)n * 16 + cob + co) * 16 + ph) * 512 + pw] = pooled[co];
  }
  int lane = threadIdx.x & 63;
#pragma unroll
  for (int co = 0; co < 8; co++) {
    float v = pooled[co];
    for (int off = 32; off; off >>= 1) v += __shfl_down(v, off);
    if (lane == 0) atomicAdd(&sesum[n * 16 + cob + co], v);
  }
}

// ---------------- SE MLP (generic): mean -> relu fc -> sigmoid fc ----------------
__global__ void k_se(const float* __restrict__ sesum, int C, int Cr, float invcnt,
                     const float* __restrict__ w1, const float* __restrict__ b1,
                     const float* __restrict__ w2, const float* __restrict__ b2,
                     float* __restrict__ s)
{
  int n = blockIdx.x * blockDim.x + threadIdx.x;
  if (n >= 288) return;
  float y[32], t[8];
  for (int c = 0; c < C; c++) y[c] = sesum[n * C + c] * invcnt;
  for (int r = 0; r < Cr; r++) {
    float a = b1[r];
    for (int c = 0; c < C; c++) a += y[c] * w1[r * C + c];
    t[r] = fmaxf(a, 0.f);
  }
  for (int c = 0; c < C; c++) {
    float a = b2[c];
    for (int r = 0; r < Cr; r++) a += t[r] * w2[c * Cr + r];
    s[n * C + c] = 1.f / (1.f + expf(-a));
  }
}

// ---------------- conv2 (SE1 folded) + bn2 + relu + pool + SE2-sum ----------------
__global__ __launch_bounds__(512) void k_conv2(
    const float* __restrict__ h1, const float* __restrict__ w,
    const float* __restrict__ cb, const float* __restrict__ bs,
    const float* __restrict__ bb, const float* __restrict__ bm,
    const float* __restrict__ bv,
    const float* __restrict__ s1,
    float* __restrict__ h2, float* __restrict__ sesum)
{
  int bid = blockIdx.x;                 // n*8 + ph
  int n = bid >> 3, ph = bid & 7;
  int cog = threadIdx.x >> 7;           // 0..3 -> co slice cog*8..cog*8+7
  int wp = threadIdx.x & 127;           // pooled col 0..127
  __shared__ float wl[16][3][3][32];    // bn scale * se1 scale folded
  __shared__ float bi[32];
  const float* s1n = s1 + n * 16;
  for (int i = threadIdx.x; i < 4608; i += 512) {
    int co = i / 144, r = i % 144, ci = r / 9, kk = r % 9;
    float s = bs[co] * rsqrtf(bv[co] + 1e-5f);
    wl[ci][kk / 3][kk % 3][co] = w[i] * s * s1n[ci];
  }
  if (threadIdx.x < 32) {
    int c = threadIdx.x;
    float s = bs[c] * rsqrtf(bv[c] + 1e-5f);
    bi[c] = bb[c] + (cb[c] - bm[c]) * s;
  }
  __syncthreads();
  const float* hn = h1 + (size_t)n * 16 * 16 * 512;
  const bool r0ok = (ph > 0), r3ok = (ph < 7);
  const int col4 = 4 * wp;
  const int cob = cog * 8;
  float acc[2][2][8];
#pragma unroll
  for (int cr = 0; cr < 2; cr++)
#pragma unroll
    for (int cc = 0; cc < 2; cc++)
#pragma unroll
      for (int co = 0; co < 8; co++) acc[cr][cc][co] = 0.f;
#pragma unroll 2
  for (int ci = 0; ci < 16; ci++) {
    const float* base = hn + (ci * 16 + 2 * ph - 1) * 512;
    float strip[4][5];
#pragma unroll
    for (int r = 0; r < 4; r++) {
      bool ok = (r == 0) ? r0ok : ((r == 3) ? r3ok : true);
      const float* hr = base + r * 512;
      if (ok) {
        float4 v4 = *reinterpret_cast<const float4*>(hr + col4);
        strip[r][0] = wp ? hr[col4 - 1] : 0.f;
        strip[r][1] = v4.x; strip[r][2] = v4.y; strip[r][3] = v4.z; strip[r][4] = v4.w;
      } else {
        strip[r][0] = strip[r][1] = strip[r][2] = strip[r][3] = strip[r][4] = 0.f;
      }
    }
#pragma unroll
    for (int cr = 0; cr < 2; cr++) {
#pragma unroll
      for (int kh = 0; kh < 3; kh++) {
        int r = cr + kh;
#pragma unroll
        for (int kw = 0; kw < 3; kw++) {
          float v0 = strip[r][kw], v1 = strip[r][2 + kw];
#pragma unroll
          for (int co = 0; co < 8; co++) {
            float wv = wl[ci][kh][kw][cob + co];
            acc[cr][0][co] = fmaf(v0, wv, acc[cr][0][co]);
            acc[cr][1][co] = fmaf(v1, wv, acc[cr][1][co]);
          }
        }
      }
    }
  }
  float pooled[8];
#pragma unroll
  for (int co = 0; co < 8; co++) {
    float m = fmaxf(fmaxf(acc[0][0][co], acc[0][1][co]),
                    fmaxf(acc[1][0][co], acc[1][1][co]));
    pooled[co] = fmaxf(m + bi[cob + co], 0.f);
    h2[(((size_t)n * 32 + cob + co) * 8 + ph) * 128 + wp] = pooled[co];
  }
  int lane = threadIdx.x & 63;
#pragma unroll
  for (int co = 0; co < 8; co++) {
    float v = pooled[co];
    for (int off = 32; off; off >>= 1) v += __shfl_down(v, off);
    if (lane == 0) atomicAdd(&sesum[n * 32 + cob + co], v);
  }
}

// ---------------- conv3 (SE2 folded) + bn3 + relu + global mean ----------------
__global__ __launch_bounds__(256) void k_conv3(
    const float* __restrict__ h2, const float* __restrict__ w,
    const float* __restrict__ cb, const float* __restrict__ bs,
    const float* __restrict__ bb, const float* __restrict__ bm,
    const float* __restrict__ bv,
    const float* __restrict__ s2, float* __restrict__ h3)
{
  int bid = blockIdx.x;                 // n*4 + cog (16 out channels per cog)
  int n = bid >> 2, cog = bid & 3;
  int hh = threadIdx.x >> 5;            // conv row 0..7
  int t = threadIdx.x & 31;             // conv col pair: cols 2t, 2t+1
  __shared__ float wl[32][3][3][16];    // [ci][kh][kw][k], 18 KB, scales folded
  __shared__ float bi[16];
  __shared__ float red[4][16];
  const float* s2n = s2 + n * 32;
  for (int i = threadIdx.x; i < 4608; i += 256) {
    int k = i / 288, r = i % 288, ci = r / 9, kk = r % 9;
    int co = cog * 16 + k;
    float s = bs[co] * rsqrtf(bv[co] + 1e-5f);
    wl[ci][kk / 3][kk % 3][k] = w[(size_t)co * 288 + r] * s * s2n[ci];
  }
  if (threadIdx.x < 16) {
    int c = cog * 16 + threadIdx.x;
    float s = bs[c] * rsqrtf(bv[c] + 1e-5f);
    bi[threadIdx.x] = bb[c] + (cb[c] - bm[c]) * s;
  }
  __syncthreads();
  const float* hn = h2 + (size_t)n * 32 * 8 * 128;
  const bool r0ok = (hh > 0), r2ok = (hh < 7);
  const int col4 = 4 * t;
  float acc[2][16];
#pragma unroll
  for (int cc = 0; cc < 2; cc++)
#pragma unroll
    for (int k = 0; k < 16; k++) acc[cc][k] = 0.f;
#pragma unroll 2
  for (int ci = 0; ci < 32; ci++) {
    const float* base = hn + (ci * 8 + hh - 1) * 128;
    float strip[3][5];
#pragma unroll
    for (int r = 0; r < 3; r++) {
      bool ok = (r == 0) ? r0ok : ((r == 2) ? r2ok : true);
      const float* hr = base + r * 128;
      if (ok) {
        float4 v4 = *reinterpret_cast<const float4*>(hr + col4);
        strip[r][0] = t ? hr[col4 - 1] : 0.f;
        strip[r][1] = v4.x; strip[r][2] = v4.y; strip[r][3] = v4.z; strip[r][4] = v4.w;
      } else {
        strip[r][0] = strip[r][1] = strip[r][2] = strip[r][3] = strip[r][4] = 0.f;
      }
    }
#pragma unroll
    for (int kh = 0; kh < 3; kh++) {
#pragma unroll
      for (int kw = 0; kw < 3; kw++) {
        float v0 = strip[kh][kw], v1 = strip[kh][2 + kw];
#pragma unroll
        for (int k = 0; k < 16; k++) {
          float wv = wl[ci][kh][kw][k];
          acc[0][k] = fmaf(v0, wv, acc[0][k]);
          acc[1][k] = fmaf(v1, wv, acc[1][k]);
        }
      }
    }
  }
#pragma unroll
  for (int k = 0; k < 16; k++)
    acc[0][k] = fmaxf(acc[0][k] + bi[k], 0.f) + fmaxf(acc[1][k] + bi[k], 0.f);
  int lane = threadIdx.x & 63, wv = threadIdx.x >> 6;
#pragma unroll
  for (int k = 0; k < 16; k++) {
    float v = acc[0][k];
    for (int off = 32; off; off >>= 1) v += __shfl_down(v, off);
    if (lane == 0) red[wv][k] = v;
  }
  __syncthreads();
  if (threadIdx.x < 16) {
    int k = threadIdx.x;
    float tt = red[0][k] + red[1][k] + red[2][k] + red[3][k];
    h3[n * 64 + cog * 16 + k] = tt * (1.f / 512.f);
  }
}

// ---------------- head: edge_fc + GNN scatter + e2n + attention + outputs ----------------
__global__ __launch_bounds__(256) void k_head(
    const float* __restrict__ h3,
    const float* __restrict__ efw, const float* __restrict__ efb,
    const float* __restrict__ ew,
    const float* __restrict__ e2nw, const float* __restrict__ e2nb,
    const float* __restrict__ a1w, const float* __restrict__ a1b,
    const float* __restrict__ a2w,
    const float* __restrict__ clsw, const float* __restrict__ clsb,
    const float* __restrict__ regw, const float* __restrict__ regb,
    float* __restrict__ out)
{
  int b = blockIdx.x;
  int tid = threadIdx.x;
  __shared__ float ef[36][64];      // weighted edge features
  __shared__ float nin[12][64];
  __shared__ float nd[12][128];
  __shared__ float tmp[12][64];
  __shared__ float spw[36], aw[12], scv[12], g[128], ea[36];
  if (tid < 36) {
    float xw = ew[tid];
    spw[tid] = (xw > 20.f) ? xw : log1pf(expf(xw));   // softplus
  }
  __syncthreads();
  for (int idx = tid; idx < 36 * 64; idx += 256) {
    int e = idx >> 6, d = idx & 63;
    const float* hr = h3 + (size_t)(b * 36 + e) * 64;
    const float* wr = efw + d * 64;
    float a = efb[d];
    for (int k = 0; k < 64; k++) a += hr[k] * wr[k];
    ef[e][d] = fmaxf(a, 0.f) * spw[e];
  }
  __syncthreads();
  for (int idx = tid; idx < 12 * 64; idx += 256) {
    int j = idx >> 6, d = idx & 63;
    float a = 0.f;
    if (j < 6) { for (int i = 0; i < 6; i++) a += ef[j * 6 + i][d]; }
    else       { for (int i = 0; i < 6; i++) a += ef[i * 6 + (j - 6)][d]; }
    nin[j][d] = a;
  }
  __syncthreads();
  for (int idx = tid; idx < 12 * 128; idx += 256) {
    int j = idx >> 7, d = idx & 127;
    const float* wr = e2nw + d * 64;
    float a = e2nb[d];
    for (int k = 0; k < 64; k++) a += nin[j][k] * wr[k];
    nd[j][d] = fmaxf(a, 0.f);
  }
  __syncthreads();
  for (int idx = tid; idx < 12 * 64; idx += 256) {
    int j = idx >> 6, hh = idx & 63;
    const float* wr = a1w + hh * 128;
    float a = a1b[hh];
    for (int k = 0; k < 128; k++) a += nd[j][k] * wr[k];
    tmp[j][hh] = tanhf(a) * a2w[hh];
  }
  __syncthreads();
  if (tid < 12) {
    float a = 0.f;
    for (int h = 0; h < 64; h++) a += tmp[tid][h];
    scv[tid] = a;
  }
  __syncthreads();
  if (tid == 0) {
    float m = scv[0];
    for (int j = 1; j < 12; j++) m = fmaxf(m, scv[j]);
    float s = 0.f;
    for (int j = 0; j < 12; j++) { float z = expf(scv[j] - m); aw[j] = z; s += z; }
    float inv = 1.f / s;
    for (int j = 0; j < 12; j++) aw[j] *= inv;
    float rs = 0.f;
    for (int e = 0; e < 36; e++) { float r = aw[e / 6] * aw[6 + e % 6]; ea[e] = r; rs += r; }
    float inv2 = 1.f / (rs + 1e-8f);
    for (int e = 0; e < 36; e++) ea[e] *= inv2;
  }
  __syncthreads();
  if (tid < 36) out[96 + b * 36 + tid] = ea[tid];
  if (tid < 128) {
    float a = 0.f;
    for (int j = 0; j < 12; j++) a += nd[j][tid] * aw[j];
    g[tid] = a;
  }
  __syncthreads();
  if (tid < 3) {
    const float* wr = regw + tid * 128;
    float a = regb[tid];
    for (int k = 0; k < 128; k++) a += g[k] * wr[k];
    out[b * 3 + tid] = a;
  }
  if (tid >= 64 && tid < 73) {
    int i = tid - 64;
    const float* wr = clsw + i * 128;
    float a = clsb[i];
    for (int k = 0; k < 128; k++) a += g[k] * wr[k];
    out[24 + b * 9 + i] = a;
  }
}

extern "C" void kernel_launch(void* const* d_in, const int* in_sizes, int n_in,
                              void* d_out, int out_size, void* d_ws, size_t ws_size,
                              hipStream_t stream) {
  const float* x      = (const float*)d_in[0];
  const float* c1w    = (const float*)d_in[1];
  const float* c1b    = (const float*)d_in[2];
  const float* bn1s   = (const float*)d_in[3];
  const float* bn1b   = (const float*)d_in[4];
  const float* bn1m   = (const float*)d_in[5];
  const float* bn1v   = (const float*)d_in[6];
  const float* se1w1  = (const float*)d_in[7];
  const float* se1b1  = (const float*)d_in[8];
  const float* se1w2  = (const float*)d_in[9];
  const float* se1b2  = (const float*)d_in[10];
  const float* c2w    = (const float*)d_in[11];
  const float* c2b    = (const float*)d_in[12];
  const float* bn2s   = (const float*)d_in[13];
  const float* bn2b   = (const float*)d_in[14];
  const float* bn2m   = (const float*)d_in[15];
  const float* bn2v   = (const float*)d_in[16];
  const float* se2w1  = (const float*)d_in[17];
  const float* se2b1  = (const float*)d_in[18];
  const float* se2w2  = (const float*)d_in[19];
  const float* se2b2  = (const float*)d_in[20];
  const float* c3w    = (const float*)d_in[21];
  const float* c3b    = (const float*)d_in[22];
  const float* bn3s   = (const float*)d_in[23];
  const float* bn3b   = (const float*)d_in[24];
  const float* bn3m   = (const float*)d_in[25];
  const float* bn3v   = (const float*)d_in[26];
  const float* efw    = (const float*)d_in[27];
  const float* efb    = (const float*)d_in[28];
  const float* ew     = (const float*)d_in[29];
  const float* e2nw   = (const float*)d_in[30];
  const float* e2nb   = (const float*)d_in[31];
  const float* a1w    = (const float*)d_in[32];
  const float* a1b    = (const float*)d_in[33];
  const float* a2w    = (const float*)d_in[34];
  const float* clsw   = (const float*)d_in[35];
  const float* clsb   = (const float*)d_in[36];
  const float* regw   = (const float*)d_in[37];
  const float* regb   = (const float*)d_in[38];

  float* ws = (float*)d_ws;
  float* h1     = ws;                        // 288*16*16*512 = 37,748,736 f
  float* h2     = h1 + 37748736;             // 288*32*8*128  =  9,437,184 f
  float* sesum1 = h2 + 9437184;              // 4608 f
  float* s1     = sesum1 + 4608;             // 4608 f
  float* sesum2 = s1 + 4608;                 // 9216 f
  float* s2     = sesum2 + 9216;             // 9216 f
  float* h3     = s2 + 9216;                 // 18432 f

  hipMemsetAsync(sesum1, 0, 4608 * sizeof(float), stream);
  hipMemsetAsync(sesum2, 0, 9216 * sizeof(float), stream);

  k_conv1<<<288 * 32, 512, 0, stream>>>(x, c1w, c1b, bn1s, bn1b, bn1m, bn1v, h1, sesum1);
  k_se<<<5, 64, 0, stream>>>(sesum1, 16, 4, 1.f / 8192.f, se1w1, se1b1, se1w2, se1b2, s1);
  k_conv2<<<288 * 8, 512, 0, stream>>>(h1, c2w, c2b, bn2s, bn2b, bn2m, bn2v, s1, h2, sesum2);
  k_se<<<5, 64, 0, stream>>>(sesum2, 32, 8, 1.f / 1024.f, se2w1, se2b1, se2w2, se2b2, s2);
  k_conv3<<<288 * 4, 256, 0, stream>>>(h2, c3w, c3b, bn3s, bn3b, bn3m, bn3v, s2, h3);
  k_head<<<8, 256, 0, stream>>>(h3, efw, efb, ew, e2nw, e2nb, a1w, a1b, a2w,
                                clsw, clsb, regw, regb, (float*)d_out);
}

// Round 5
// 815.564 us; speedup vs baseline: 6.0960x; 1.7574x over previous
//
#include <hip/hip_runtime.h>
#include <math.h>

// Model: PINNDamageLocator
// conv1: (288,4,32,2048) -> bn+relu -> pool -> (288,16,16,512), SE1
// conv2: -> bn+relu -> pool -> (288,32,8,128), SE2
// conv3: -> bn+relu -> mean -> (288,64)
// then edge_fc + GNN + attention heads -> (reg[8,3], cls[8,9], ea[8,36])
//
// Dataflow: each thread owns ONE pooled output column and a SLICE (8 or 16)
// of output channels; the 4 input rows feeding its 2x2 pooling window are
// loaded once per ci as a batch of independent float4+halo loads, then
// consumed by ~288 FMAs from LDS-broadcast weights.
// R3 post-mortem: __launch_bounds__(256,4) forced VGPR=64 -> scratch spill
//   (4.5 GB HBM writes). Never use the min-waves clamp here.
// R4 post-mortem: full `#pragma unroll` on the ci loop hoisted ALL
//   iterations' strip loads -> >128 live regs -> spill again (1.5 GB scratch
//   writes). ci loops MUST be `#pragma unroll 1`: one strip live at a time,
//   loads batched within the iteration, waves provide cross-iter overlap.

// ---------------- conv1 + bn1 + relu + maxpool + SE1-sum ----------------
__global__ __launch_bounds__(512) void k_conv1(
    const float* __restrict__ x, const float* __restrict__ w,
    const float* __restrict__ cb, const float* __restrict__ bs,
    const float* __restrict__ bb, const float* __restrict__ bm,
    const float* __restrict__ bv,
    float* __restrict__ h1, float* __restrict__ sesum)
{
  int bid = blockIdx.x;                  // n*32 + ph*2 + half
  int n = bid >> 5, rem = bid & 31, ph = rem >> 1, half = rem & 1;
  int cog = threadIdx.x >> 8;            // 0,1 -> co slice cog*8..cog*8+7
  int pw = (half << 8) + (threadIdx.x & 255);   // pooled col 0..511
  __shared__ float wl[4][3][3][16];      // [ci][kh][kw][co], bn-scale folded
  __shared__ float bi[16];
  for (int i = threadIdx.x; i < 576; i += 512) {
    int co = i / 36, r = i % 36, ci = r / 9, kk = r % 9;
    float s = bs[co] * rsqrtf(bv[co] + 1e-5f);
    wl[ci][kk / 3][kk % 3][co] = w[i] * s;
  }
  if (threadIdx.x < 16) {
    int c = threadIdx.x;
    float s = bs[c] * rsqrtf(bv[c] + 1e-5f);
    bi[c] = bb[c] + (cb[c] - bm[c]) * s;
  }
  __syncthreads();
  const float* xn = x + (size_t)n * 4 * 32 * 2048;
  const bool r0ok = (ph > 0), r3ok = (ph < 15);
  const int col4 = 4 * pw;
  const int cob = cog * 8;
  float acc[2][2][8];
#pragma unroll
  for (int cr = 0; cr < 2; cr++)
#pragma unroll
    for (int cc = 0; cc < 2; cc++)
#pragma unroll
      for (int co = 0; co < 8; co++) acc[cr][cc][co] = 0.f;
#pragma unroll 1
  for (int ci = 0; ci < 4; ci++) {
    const float* base = xn + (ci * 32 + 2 * ph - 1) * 2048;
    float strip[4][5];
#pragma unroll
    for (int r = 0; r < 4; r++) {
      bool ok = (r == 0) ? r0ok : ((r == 3) ? r3ok : true);
      const float* xr = base + r * 2048;
      if (ok) {
        float4 v4 = *reinterpret_cast<const float4*>(xr + col4);
        strip[r][0] = pw ? xr[col4 - 1] : 0.f;
        strip[r][1] = v4.x; strip[r][2] = v4.y; strip[r][3] = v4.z; strip[r][4] = v4.w;
      } else {
        strip[r][0] = strip[r][1] = strip[r][2] = strip[r][3] = strip[r][4] = 0.f;
      }
    }
#pragma unroll
    for (int cr = 0; cr < 2; cr++) {
#pragma unroll
      for (int kh = 0; kh < 3; kh++) {
        int r = cr + kh;
#pragma unroll
        for (int kw = 0; kw < 3; kw++) {
          float v0 = strip[r][kw], v1 = strip[r][2 + kw];
#pragma unroll
          for (int co = 0; co < 8; co++) {
            float wv = wl[ci][kh][kw][cob + co];
            acc[cr][0][co] = fmaf(v0, wv, acc[cr][0][co]);
            acc[cr][1][co] = fmaf(v1, wv, acc[cr][1][co]);
          }
        }
      }
    }
  }
  float pooled[8];
#pragma unroll
  for (int co = 0; co < 8; co++) {
    float m = fmaxf(fmaxf(acc[0][0][co], acc[0][1][co]),
                    fmaxf(acc[1][0][co], acc[1][1][co]));
    pooled[co] = fmaxf(m + bi[cob + co], 0.f);
    h1[(((size_t)n * 16 + cob + co) * 16 + ph) * 512 + pw] = pooled[co];
  }
  int lane = threadIdx.x & 63;
#pragma unroll
  for (int co = 0; co < 8; co++) {
    float v = pooled[co];
    for (int off = 32; off; off >>= 1) v += __shfl_down(v, off);
    if (lane == 0) atomicAdd(&sesum[n * 16 + cob + co], v);
  }
}

// ---------------- SE MLP (generic): mean -> relu fc -> sigmoid fc ----------------
__global__ void k_se(const float* __restrict__ sesum, int C, int Cr, float invcnt,
                     const float* __restrict__ w1, const float* __restrict__ b1,
                     const float* __restrict__ w2, const float* __restrict__ b2,
                     float* __restrict__ s)
{
  int n = blockIdx.x * blockDim.x + threadIdx.x;
  if (n >= 288) return;
  float y[32], t[8];
  for (int c = 0; c < C; c++) y[c] = sesum[n * C + c] * invcnt;
  for (int r = 0; r < Cr; r++) {
    float a = b1[r];
    for (int c = 0; c < C; c++) a += y[c] * w1[r * C + c];
    t[r] = fmaxf(a, 0.f);
  }
  for (int c = 0; c < C; c++) {
    float a = b2[c];
    for (int r = 0; r < Cr; r++) a += t[r] * w2[c * Cr + r];
    s[n * C + c] = 1.f / (1.f + expf(-a));
  }
}

// ---------------- conv2 (SE1 folded) + bn2 + relu + pool + SE2-sum ----------------
__global__ __launch_bounds__(512) void k_conv2(
    const float* __restrict__ h1, const float* __restrict__ w,
    const float* __restrict__ cb, const float* __restrict__ bs,
    const float* __restrict__ bb, const float* __restrict__ bm,
    const float* __restrict__ bv,
    const float* __restrict__ s1,
    float* __restrict__ h2, float* __restrict__ sesum)
{
  int bid = blockIdx.x;                 // n*8 + ph
  int n = bid >> 3, ph = bid & 7;
  int cog = threadIdx.x >> 7;           // 0..3 -> co slice cog*8..cog*8+7
  int wp = threadIdx.x & 127;           // pooled col 0..127
  __shared__ float wl[16][3][3][32];    // bn scale * se1 scale folded
  __shared__ float bi[32];
  const float* s1n = s1 + n * 16;
  for (int i = threadIdx.x; i < 4608; i += 512) {
    int co = i / 144, r = i % 144, ci = r / 9, kk = r % 9;
    float s = bs[co] * rsqrtf(bv[co] + 1e-5f);
    wl[ci][kk / 3][kk % 3][co] = w[i] * s * s1n[ci];
  }
  if (threadIdx.x < 32) {
    int c = threadIdx.x;
    float s = bs[c] * rsqrtf(bv[c] + 1e-5f);
    bi[c] = bb[c] + (cb[c] - bm[c]) * s;
  }
  __syncthreads();
  const float* hn = h1 + (size_t)n * 16 * 16 * 512;
  const bool r0ok = (ph > 0), r3ok = (ph < 7);
  const int col4 = 4 * wp;
  const int cob = cog * 8;
  float acc[2][2][8];
#pragma unroll
  for (int cr = 0; cr < 2; cr++)
#pragma unroll
    for (int cc = 0; cc < 2; cc++)
#pragma unroll
      for (int co = 0; co < 8; co++) acc[cr][cc][co] = 0.f;
#pragma unroll 1
  for (int ci = 0; ci < 16; ci++) {
    const float* base = hn + (ci * 16 + 2 * ph - 1) * 512;
    float strip[4][5];
#pragma unroll
    for (int r = 0; r < 4; r++) {
      bool ok = (r == 0) ? r0ok : ((r == 3) ? r3ok : true);
      const float* hr = base + r * 512;
      if (ok) {
        float4 v4 = *reinterpret_cast<const float4*>(hr + col4);
        strip[r][0] = wp ? hr[col4 - 1] : 0.f;
        strip[r][1] = v4.x; strip[r][2] = v4.y; strip[r][3] = v4.z; strip[r][4] = v4.w;
      } else {
        strip[r][0] = strip[r][1] = strip[r][2] = strip[r][3] = strip[r][4] = 0.f;
      }
    }
#pragma unroll
    for (int cr = 0; cr < 2; cr++) {
#pragma unroll
      for (int kh = 0; kh < 3; kh++) {
        int r = cr + kh;
#pragma unroll
        for (int kw = 0; kw < 3; kw++) {
          float v0 = strip[r][kw], v1 = strip[r][2 + kw];
#pragma unroll
          for (int co = 0; co < 8; co++) {
            float wv = wl[ci][kh][kw][cob + co];
            acc[cr][0][co] = fmaf(v0, wv, acc[cr][0][co]);
            acc[cr][1][co] = fmaf(v1, wv, acc[cr][1][co]);
          }
        }
      }
    }
  }
  float pooled[8];
#pragma unroll
  for (int co = 0; co < 8; co++) {
    float m = fmaxf(fmaxf(acc[0][0][co], acc[0][1][co]),
                    fmaxf(acc[1][0][co], acc[1][1][co]));
    pooled[co] = fmaxf(m + bi[cob + co], 0.f);
    h2[(((size_t)n * 32 + cob + co) * 8 + ph) * 128 + wp] = pooled[co];
  }
  int lane = threadIdx.x & 63;
#pragma unroll
  for (int co = 0; co < 8; co++) {
    float v = pooled[co];
    for (int off = 32; off; off >>= 1) v += __shfl_down(v, off);
    if (lane == 0) atomicAdd(&sesum[n * 32 + cob + co], v);
  }
}

// ---------------- conv3 (SE2 folded) + bn3 + relu + global mean ----------------
__global__ __launch_bounds__(256) void k_conv3(
    const float* __restrict__ h2, const float* __restrict__ w,
    const float* __restrict__ cb, const float* __restrict__ bs,
    const float* __restrict__ bb, const float* __restrict__ bm,
    const float* __restrict__ bv,
    const float* __restrict__ s2, float* __restrict__ h3)
{
  int bid = blockIdx.x;                 // n*4 + cog (16 out channels per cog)
  int n = bid >> 2, cog = bid & 3;
  int hh = threadIdx.x >> 5;            // conv row 0..7
  int t = threadIdx.x & 31;             // conv col pair: cols 2t, 2t+1
  __shared__ float wl[32][3][3][16];    // [ci][kh][kw][k], 18 KB, scales folded
  __shared__ float bi[16];
  __shared__ float red[4][16];
  const float* s2n = s2 + n * 32;
  for (int i = threadIdx.x; i < 4608; i += 256) {
    int k = i / 288, r = i % 288, ci = r / 9, kk = r % 9;
    int co = cog * 16 + k;
    float s = bs[co] * rsqrtf(bv[co] + 1e-5f);
    wl[ci][kk / 3][kk % 3][k] = w[(size_t)co * 288 + r] * s * s2n[ci];
  }
  if (threadIdx.x < 16) {
    int c = cog * 16 + threadIdx.x;
    float s = bs[c] * rsqrtf(bv[c] + 1e-5f);
    bi[threadIdx.x] = bb[c] + (cb[c] - bm[c]) * s;
  }
  __syncthreads();
  const float* hn = h2 + (size_t)n * 32 * 8 * 128;
  const bool r0ok = (hh > 0), r2ok = (hh < 7);
  const int col4 = 4 * t;
  float acc[2][16];
#pragma unroll
  for (int cc = 0; cc < 2; cc++)
#pragma unroll
    for (int k = 0; k < 16; k++) acc[cc][k] = 0.f;
#pragma unroll 1
  for (int ci = 0; ci < 32; ci++) {
    const float* base = hn + (ci * 8 + hh - 1) * 128;
    float strip[3][5];
#pragma unroll
    for (int r = 0; r < 3; r++) {
      bool ok = (r == 0) ? r0ok : ((r == 2) ? r2ok : true);
      const float* hr = base + r * 128;
      if (ok) {
        float4 v4 = *reinterpret_cast<const float4*>(hr + col4);
        strip[r][0] = t ? hr[col4 - 1] : 0.f;
        strip[r][1] = v4.x; strip[r][2] = v4.y; strip[r][3] = v4.z; strip[r][4] = v4.w;
      } else {
        strip[r][0] = strip[r][1] = strip[r][2] = strip[r][3] = strip[r][4] = 0.f;
      }
    }
#pragma unroll
    for (int kh = 0; kh < 3; kh++) {
#pragma unroll
      for (int kw = 0; kw < 3; kw++) {
        float v0 = strip[kh][kw], v1 = strip[kh][2 + kw];
#pragma unroll
        for (int k = 0; k < 16; k++) {
          float wv = wl[ci][kh][kw][k];
          acc[0][k] = fmaf(v0, wv, acc[0][k]);
          acc[1][k] = fmaf(v1, wv, acc[1][k]);
        }
      }
    }
  }
#pragma unroll
  for (int k = 0; k < 16; k++)
    acc[0][k] = fmaxf(acc[0][k] + bi[k], 0.f) + fmaxf(acc[1][k] + bi[k], 0.f);
  int lane = threadIdx.x & 63, wv = threadIdx.x >> 6;
#pragma unroll
  for (int k = 0; k < 16; k++) {
    float v = acc[0][k];
    for (int off = 32; off; off >>= 1) v += __shfl_down(v, off);
    if (lane == 0) red[wv][k] = v;
  }
  __syncthreads();
  if (threadIdx.x < 16) {
    int k = threadIdx.x;
    float tt = red[0][k] + red[1][k] + red[2][k] + red[3][k];
    h3[n * 64 + cog * 16 + k] = tt * (1.f / 512.f);
  }
}

// ---------------- head: edge_fc + GNN scatter + e2n + attention + outputs ----------------
__global__ __launch_bounds__(256) void k_head(
    const float* __restrict__ h3,
    const float* __restrict__ efw, const float* __restrict__ efb,
    const float* __restrict__ ew,
    const float* __restrict__ e2nw, const float* __restrict__ e2nb,
    const float* __restrict__ a1w, const float* __restrict__ a1b,
    const float* __restrict__ a2w,
    const float* __restrict__ clsw, const float* __restrict__ clsb,
    const float* __restrict__ regw, const float* __restrict__ regb,
    float* __restrict__ out)
{
  int b = blockIdx.x;
  int tid = threadIdx.x;
  __shared__ float ef[36][64];      // weighted edge features
  __shared__ float nin[12][64];
  __shared__ float nd[12][128];
  __shared__ float tmp[12][64];
  __shared__ float spw[36], aw[12], scv[12], g[128], ea[36];
  if (tid < 36) {
    float xw = ew[tid];
    spw[tid] = (xw > 20.f) ? xw : log1pf(expf(xw));   // softplus
  }
  __syncthreads();
  for (int idx = tid; idx < 36 * 64; idx += 256) {
    int e = idx >> 6, d = idx & 63;
    const float* hr = h3 + (size_t)(b * 36 + e) * 64;
    const float* wr = efw + d * 64;
    float a = efb[d];
    for (int k = 0; k < 64; k++) a += hr[k] * wr[k];
    ef[e][d] = fmaxf(a, 0.f) * spw[e];
  }
  __syncthreads();
  for (int idx = tid; idx < 12 * 64; idx += 256) {
    int j = idx >> 6, d = idx & 63;
    float a = 0.f;
    if (j < 6) { for (int i = 0; i < 6; i++) a += ef[j * 6 + i][d]; }
    else       { for (int i = 0; i < 6; i++) a += ef[i * 6 + (j - 6)][d]; }
    nin[j][d] = a;
  }
  __syncthreads();
  for (int idx = tid; idx < 12 * 128; idx += 256) {
    int j = idx >> 7, d = idx & 127;
    const float* wr = e2nw + d * 64;
    float a = e2nb[d];
    for (int k = 0; k < 64; k++) a += nin[j][k] * wr[k];
    nd[j][d] = fmaxf(a, 0.f);
  }
  __syncthreads();
  for (int idx = tid; idx < 12 * 64; idx += 256) {
    int j = idx >> 6, hh = idx & 63;
    const float* wr = a1w + hh * 128;
    float a = a1b[hh];
    for (int k = 0; k < 128; k++) a += nd[j][k] * wr[k];
    tmp[j][hh] = tanhf(a) * a2w[hh];
  }
  __syncthreads();
  if (tid < 12) {
    float a = 0.f;
    for (int h = 0; h < 64; h++) a += tmp[tid][h];
    scv[tid] = a;
  }
  __syncthreads();
  if (tid == 0) {
    float m = scv[0];
    for (int j = 1; j < 12; j++) m = fmaxf(m, scv[j]);
    float s = 0.f;
    for (int j = 0; j < 12; j++) { float z = expf(scv[j] - m); aw[j] = z; s += z; }
    float inv = 1.f / s;
    for (int j = 0; j < 12; j++) aw[j] *= inv;
    float rs = 0.f;
    for (int e = 0; e < 36; e++) { float r = aw[e / 6] * aw[6 + e % 6]; ea[e] = r; rs += r; }
    float inv2 = 1.f / (rs + 1e-8f);
    for (int e = 0; e < 36; e++) ea[e] *= inv2;
  }
  __syncthreads();
  if (tid < 36) out[96 + b * 36 + tid] = ea[tid];
  if (tid < 128) {
    float a = 0.f;
    for (int j = 0; j < 12; j++) a += nd[j][tid] * aw[j];
    g[tid] = a;
  }
  __syncthreads();
  if (tid < 3) {
    const float* wr = regw + tid * 128;
    float a = regb[tid];
    for (int k = 0; k < 128; k++) a += g[k] * wr[k];
    out[b * 3 + tid] = a;
  }
  if (tid >= 64 && tid < 73) {
    int i = tid - 64;
    const float* wr = clsw + i * 128;
    float a = clsb[i];
    for (int k = 0; k < 128; k++) a += g[k] * wr[k];
    out[24 + b * 9 + i] = a;
  }
}

extern "C" void kernel_launch(void* const* d_in, const int* in_sizes, int n_in,
                              void* d_out, int out_size, void* d_ws, size_t ws_size,
                              hipStream_t stream) {
  const float* x      = (const float*)d_in[0];
  const float* c1w    = (const float*)d_in[1];
  const float* c1b    = (const float*)d_in[2];
  const float* bn1s   = (const float*)d_in[3];
  const float* bn1b   = (const float*)d_in[4];
  const float* bn1m   = (const float*)d_in[5];
  const float* bn1v   = (const float*)d_in[6];
  const float* se1w1  = (const float*)d_in[7];
  const float* se1b1  = (const float*)d_in[8];
  const float* se1w2  = (const float*)d_in[9];
  const float* se1b2  = (const float*)d_in[10];
  const float* c2w    = (const float*)d_in[11];
  const float* c2b    = (const float*)d_in[12];
  const float* bn2s   = (const float*)d_in[13];
  const float* bn2b   = (const float*)d_in[14];
  const float* bn2m   = (const float*)d_in[15];
  const float* bn2v   = (const float*)d_in[16];
  const float* se2w1  = (const float*)d_in[17];
  const float* se2b1  = (const float*)d_in[18];
  const float* se2w2  = (const float*)d_in[19];
  const float* se2b2  = (const float*)d_in[20];
  const float* c3w    = (const float*)d_in[21];
  const float* c3b    = (const float*)d_in[22];
  const float* bn3s   = (const float*)d_in[23];
  const float* bn3b   = (const float*)d_in[24];
  const float* bn3m   = (const float*)d_in[25];
  const float* bn3v   = (const float*)d_in[26];
  const float* efw    = (const float*)d_in[27];
  const float* efb    = (const float*)d_in[28];
  const float* ew     = (const float*)d_in[29];
  const float* e2nw   = (const float*)d_in[30];
  const float* e2nb   = (const float*)d_in[31];
  const float* a1w    = (const float*)d_in[32];
  const float* a1b    = (const float*)d_in[33];
  const float* a2w    = (const float*)d_in[34];
  const float* clsw   = (const float*)d_in[35];
  const float* clsb   = (const float*)d_in[36];
  const float* regw   = (const float*)d_in[37];
  const float* regb   = (const float*)d_in[38];

  float* ws = (float*)d_ws;
  float* h1     = ws;                        // 288*16*16*512 = 37,748,736 f
  float* h2     = h1 + 37748736;             // 288*32*8*128  =  9,437,184 f
  float* sesum1 = h2 + 9437184;              // 4608 f
  float* s1     = sesum1 + 4608;             // 4608 f
  float* sesum2 = s1 + 4608;                 // 9216 f
  float* s2     = sesum2 + 9216;             // 9216 f
  float* h3     = s2 + 9216;                 // 18432 f

  hipMemsetAsync(sesum1, 0, 4608 * sizeof(float), stream);
  hipMemsetAsync(sesum2, 0, 9216 * sizeof(float), stream);

  k_conv1<<<288 * 32, 512, 0, stream>>>(x, c1w, c1b, bn1s, bn1b, bn1m, bn1v, h1, sesum1);
  k_se<<<5, 64, 0, stream>>>(sesum1, 16, 4, 1.f / 8192.f, se1w1, se1b1, se1w2, se1b2, s1);
  k_conv2<<<288 * 8, 512, 0, stream>>>(h1, c2w, c2b, bn2s, bn2b, bn2m, bn2v, s1, h2, sesum2);
  k_se<<<5, 64, 0, stream>>>(sesum2, 32, 8, 1.f / 1024.f, se2w1, se2b1, se2w2, se2b2, s2);
  k_conv3<<<288 * 4, 256, 0, stream>>>(h2, c3w, c3b, bn3s, bn3b, bn3m, bn3v, s2, h3);
  k_head<<<8, 256, 0, stream>>>(h3, efw, efb, ew, e2nw, e2nb, a1w, a1b, a2w,
                                clsw, clsb, regw, regb, (float*)d_out);
}